// Round 8
// baseline (220.792 us; speedup 1.0000x reference)
//
#include <hip/hip_runtime.h>
#include <hip/hip_bf16.h>
#include <hip/hip_fp8.h>

// Self-attention: q=X@Wq.T+bq, k=..., v=...; S = causal_softmax(q k^T / 32); O = S v
// B=4, S=2048, D_IN=D_OUT=1024. fp32 in/out; internal bf16/fp8 MFMA + fp32 acc.
//
// R21 change (single, contained): 2-D XCD tiling for gemm_pv. R20 measured
// qkv at its 2-phase ceiling (60.6us, FETCH=33MB~=floor); pv's arithmetic says
// ~290MB HBM (Sb panels x8 + Vt panels x16 unshared) ~= 46us floor. New
// decode: XCD x = (z<<1)|nhalf owns all 16 mt x 4 n-blocks of one (z,nhalf):
//  - Vt working set/XCD = 4 panels (2MB, L2-resident) read by 16 mt-blocks
//    each -> B traffic 143 -> ~16MB.
//  - Sb panel fetched once per n-half (2 XCDs) -> A traffic ~36MB.
//  - balance EXACT: every XCD gets the same mt distribution (136 units),
//    longest-first (mt descending) preserved, 64 blocks/XCD = 2/CU packing.
// qkv / scores / convert byte-identical to R20 (216.1us best).
//
// MFMA fragment layouts (HW-verified per guide §3):
//  A: lane holds A[m=lane&15][k=(lane>>4)*8+j], j=0..7
//  B: lane holds B[k=(lane>>4)*8+j][n=lane&15]
//  C/D: lane holds D[row=(lane>>4)*4+e][col=lane&15], e=0..3

typedef __attribute__((ext_vector_type(8))) short short8;   // 8 bf16 = 4 VGPRs
typedef __attribute__((ext_vector_type(4))) float floatx4;  // MFMA acc
typedef __attribute__((ext_vector_type(2))) long longx2;    // 16B = 2 fp8 frags

#define SEQ   2048
#define DMODEL 1024
#define NBATCH 4
#define MTOT  (SEQ * NBATCH)

// End-of-step fence: all my stage16s (vmcnt) and my ds_reads (lgkm) done,
// then block-wide barrier. sched_barrier stops hipcc migrating ops across.
#define STEP_FENCE() do {                                              \
    asm volatile("s_waitcnt vmcnt(0) lgkmcnt(0)" ::: "memory");        \
    __builtin_amdgcn_sched_barrier(0);                                 \
    __builtin_amdgcn_s_barrier(); } while (0)

// Direct global->LDS async copy, 16B per lane. LDS dst is wave-uniform base +
// lane*16 (per-lane scatter NOT supported).
__device__ __forceinline__ void stage16(const void* g, void* l)
{
  __builtin_amdgcn_global_load_lds(
      (const __attribute__((address_space(1))) void*)g,
      (__attribute__((address_space(3))) void*)l, 16, 0, 0);
}

__device__ __forceinline__ unsigned short bf16_bits(float f)
{
  __hip_bfloat16 h = __float2bfloat16(f);
  return *(unsigned short*)&h;
}

__device__ __forceinline__ unsigned char fp8_bits(float f)
{
  __hip_fp8_e4m3 h(f);            // OCP e4m3 (gfx950), not fnuz
  return h.__x;
}

// ---------------------------------------------------------------------------
// One-kernel fp32 -> bf16 convert for all four inputs. Each block: 1024 elems.
__global__ __launch_bounds__(256) void convert_all(
    const float* __restrict__ X,  const float* __restrict__ Wq,
    const float* __restrict__ Wk, const float* __restrict__ Wv,
    __hip_bfloat16* __restrict__ Xb,  __hip_bfloat16* __restrict__ Wqb,
    __hip_bfloat16* __restrict__ Wkb, __hip_bfloat16* __restrict__ Wvb)
{
  const int b = blockIdx.x;
  const float* src; __hip_bfloat16* dst; int rel;
  if (b < 8192)       { src = X;  dst = Xb;  rel = b; }
  else if (b < 9216)  { src = Wq; dst = Wqb; rel = b - 8192; }
  else if (b < 10240) { src = Wk; dst = Wkb; rel = b - 9216; }
  else                { src = Wv; dst = Wvb; rel = b - 10240; }
  const int i = rel * 1024 + threadIdx.x * 4;
  float4 f = *(const float4*)(src + i);
  uint2 o;
  o.x = (unsigned)bf16_bits(f.x) | ((unsigned)bf16_bits(f.y) << 16);
  o.y = (unsigned)bf16_bits(f.z) | ((unsigned)bf16_bits(f.w) << 16);
  *(uint2*)(dst + i) = o;
}

// ---------------------------------------------------------------------------
// Fused QKV projection, prefetch-1 double-buffered (T3 minimum-2-phase).
// 4 waves, tile 128(m) x 128(n) x {Q,K,V}, BK=32, 48 MFMA/wave/step between
// single barriers. LDS 2 x (8+24) = 64 KB. Q,K stored fp8 e4m3 row-major;
// V stored bf16 transposed to Vt. grid = 512 flat (XCD-chunked, mt-grouped),
// 256 threads.
__global__ __launch_bounds__(256, 2) void gemm_qkv_db(
    const __hip_bfloat16* __restrict__ Xb,
    const __hip_bfloat16* __restrict__ Wqb,
    const __hip_bfloat16* __restrict__ Wkb,
    const __hip_bfloat16* __restrict__ Wvb,
    const float* __restrict__ bq, const float* __restrict__ bk, const float* __restrict__ bv,
    unsigned char* __restrict__ Qb, unsigned char* __restrict__ Kb,
    __hip_bfloat16* __restrict__ Vt)
{
  __shared__ __hip_bfloat16 As[2][128 * 32];      // 2 x 8 KB
  __shared__ __hip_bfloat16 Bs[2][3][128 * 32];   // 2 x 24 KB

  // XCD-chunked bijective swizzle (512 % 8 == 0), mt-grouped.
  const int b    = blockIdx.x;                 // 0..511
  const int orig = (b & 7) * 64 + (b >> 3);
  const int mt = orig >> 3, ng = orig & 7;
  const int m0 = mt * 128, n0 = ng * 128;

  const int tid  = threadIdx.x;
  const int lane = tid & 63;
  const int wave = tid >> 6;                   // 0..3
  const int quad = lane >> 4;
  const int r    = lane & 15;
  const int wm   = (wave >> 1) * 64;
  const int wn   = (wave & 1) * 64;
  const int srow = wave * 16 + (lane >> 2);    // 0..63
  const int scol = (lane & 3) * 8;             // 0,8,16,24

  const __hip_bfloat16* aR0 = Xb + (size_t)(m0 + srow) * DMODEL + scol;
  const __hip_bfloat16* aR1 = aR0 + (size_t)64 * DMODEL;
  const __hip_bfloat16* bR0[3], * bR1[3];
  {
    const __hip_bfloat16* Wp[3] = {Wqb, Wkb, Wvb};
#pragma unroll
    for (int w = 0; w < 3; ++w) {
      bR0[w] = Wp[w] + (size_t)(n0 + srow) * DMODEL + scol;
      bR1[w] = bR0[w] + (size_t)64 * DMODEL;
    }
  }

  floatx4 acc[3][4][4] = {};

  // Prologue: stage K-tile 0 into buffer 0, wait, publish.
  {
    stage16(aR0, As[0] + wave * 512);
    stage16(aR1, As[0] + 2048 + wave * 512);
#pragma unroll
    for (int w = 0; w < 3; ++w) {
      stage16(bR0[w], Bs[0][w] + wave * 512);
      stage16(bR1[w], Bs[0][w] + 2048 + wave * 512);
    }
    asm volatile("s_waitcnt vmcnt(0)" ::: "memory");
    __builtin_amdgcn_sched_barrier(0);
    __builtin_amdgcn_s_barrier();
  }

  for (int kt = 0; kt < 32; ++kt) {
    const int cur = kt & 1;
    // Issue next tile's staging FIRST (hides under this tile's compute).
    if (kt < 31) {
      const int k0 = (kt + 1) * 32, nb = cur ^ 1;
      stage16(aR0 + k0, As[nb] + wave * 512);
      stage16(aR1 + k0, As[nb] + 2048 + wave * 512);
#pragma unroll
      for (int w = 0; w < 3; ++w) {
        stage16(bR0[w] + k0, Bs[nb][w] + wave * 512);
        stage16(bR1[w] + k0, Bs[nb][w] + 2048 + wave * 512);
      }
    }
    // Compute current tile: 16 ds_read_b128 + 48 MFMA.
    short8 a[4];
#pragma unroll
    for (int i = 0; i < 4; ++i)
      a[i] = *(const short8*)(As[cur] + (wm + i * 16 + r) * 32 + quad * 8);
#pragma unroll
    for (int w = 0; w < 3; ++w) {
      short8 bb[4];
#pragma unroll
      for (int j = 0; j < 4; ++j)
        bb[j] = *(const short8*)(Bs[cur][w] + (wn + j * 16 + r) * 32 + quad * 8);
#pragma unroll
      for (int i = 0; i < 4; ++i)
#pragma unroll
        for (int j = 0; j < 4; ++j)
          acc[w][i][j] = __builtin_amdgcn_mfma_f32_16x16x32_bf16(a[i], bb[j], acc[w][i][j], 0, 0, 0);
    }
    STEP_FENCE();   // next tile landed (issued ~450 cyc ago) + my reads done
  }

  // Q, K: fp8 e4m3 row-major stores
  {
    unsigned char* Op[2] = {Qb, Kb};
    const float* Bp[2] = {bq, bk};
#pragma unroll
    for (int w = 0; w < 2; ++w) {
      unsigned char* out = Op[w];
#pragma unroll
      for (int j = 0; j < 4; ++j) {
        const int n = n0 + wn + j * 16 + r;
        const float bb = Bp[w][n];
#pragma unroll
        for (int i = 0; i < 4; ++i) {
          const int mbase = m0 + wm + i * 16 + quad * 4;
#pragma unroll
          for (int e = 0; e < 4; ++e)
            out[(size_t)(mbase + e) * DMODEL + n] = fp8_bits(acc[w][i][j][e] + bb);
        }
      }
    }
  }
  // V: transposed bf16 store Vt[z][d=n][pos], 8B packed per (i,j).
  {
    const int z    = m0 >> 11;           // SEQ = 2048
    const int posb = (m0 & (SEQ - 1)) + wm;
    __hip_bfloat16* vt = Vt + (size_t)z * DMODEL * SEQ;
#pragma unroll
    for (int j = 0; j < 4; ++j) {
      const int n = n0 + wn + j * 16 + r;
      const float bb = bv[n];
#pragma unroll
      for (int i = 0; i < 4; ++i) {
        const int pos = posb + i * 16 + quad * 4;
        unsigned long long pk =
            (unsigned long long)bf16_bits(acc[2][i][j][0] + bb)
          | ((unsigned long long)bf16_bits(acc[2][i][j][1] + bb) << 16)
          | ((unsigned long long)bf16_bits(acc[2][i][j][2] + bb) << 32)
          | ((unsigned long long)bf16_bits(acc[2][i][j][3] + bb) << 48);
        *(unsigned long long*)(vt + (size_t)n * SEQ + pos) = pk;
      }
    }
  }
}

// ---------------------------------------------------------------------------
// 4-wave fp8 GEMM core, prefetch-1 dbuf: C[128x128] += A * B^T, e4m3 [.,K],
// BK=64. Per step: stage t+1 (4 stage16) -> 8 ds_read_b128 -> 32 MFMA ->
// STEP_FENCE. LDS 2 x (8+8) = 32 KB.
__device__ __forceinline__ void gemm_core_4w_fp8_db(
    const unsigned char* __restrict__ A,
    const unsigned char* __restrict__ B,
    int K, int m0, int n0, int kchunks,
    unsigned char (*As)[128 * 64], unsigned char (*Bs)[128 * 64],
    floatx4 acc[4][4])
{
  const int tid  = threadIdx.x;
  const int lane = tid & 63;
  const int wave = tid >> 6;          // 0..3
  const int quad = lane >> 4;
  const int r    = lane & 15;
  const int wm   = (wave >> 1) * 64;
  const int wn   = (wave & 1) * 64;
  const int lrow = lane >> 2;         // 0..15
  const int lcol = (lane & 3) * 16;   // byte col 0,16,32,48

  const unsigned char* aB = A + (size_t)(m0 + wave * 32 + lrow) * K + lcol;
  const unsigned char* bB = B + (size_t)(n0 + wave * 32 + lrow) * K + lcol;

  // Prologue: stage tile 0.
#pragma unroll
  for (int s = 0; s < 2; ++s) {
    stage16(aB + (size_t)(16 * s) * K, As[0] + wave * 2048 + s * 1024);
    stage16(bB + (size_t)(16 * s) * K, Bs[0] + wave * 2048 + s * 1024);
  }
  asm volatile("s_waitcnt vmcnt(0)" ::: "memory");
  __builtin_amdgcn_sched_barrier(0);
  __builtin_amdgcn_s_barrier();

  for (int kt = 0; kt < kchunks; ++kt) {
    const int cur = kt & 1;
    if (kt + 1 < kchunks) {
      const int k0 = (kt + 1) * 64, nb = cur ^ 1;
#pragma unroll
      for (int s = 0; s < 2; ++s) {
        stage16(aB + (size_t)(16 * s) * K + k0, As[nb] + wave * 2048 + s * 1024);
        stage16(bB + (size_t)(16 * s) * K + k0, Bs[nb] + wave * 2048 + s * 1024);
      }
    }
    longx2 a[4], bb[4];
#pragma unroll
    for (int i = 0; i < 4; ++i) {
      a[i]  = __builtin_bit_cast(longx2, *(const int4*)(As[cur] + (wm + i * 16 + r) * 64 + quad * 16));
      bb[i] = __builtin_bit_cast(longx2, *(const int4*)(Bs[cur] + (wn + i * 16 + r) * 64 + quad * 16));
    }
#pragma unroll
    for (int kk = 0; kk < 2; ++kk)
#pragma unroll
      for (int i = 0; i < 4; ++i)
#pragma unroll
        for (int j = 0; j < 4; ++j)
          acc[i][j] = __builtin_amdgcn_mfma_f32_16x16x32_fp8_fp8(
              a[i][kk], bb[j][kk], acc[i][j], 0, 0, 0);
    STEP_FENCE();
  }
}

// ---------------------------------------------------------------------------
// 4-wave bf16 GEMM core, prefetch-1 dbuf: C[128x128] += A * B^T, BK=32.
// If SUMS: acc_s[i] += A-frag x ones (row sums of A in C-layout, fp32).
// LDS 2 x (8+8) = 32 KB.
template <bool SUMS>
__device__ __forceinline__ void gemm_core_4w_db(
    const __hip_bfloat16* __restrict__ A,
    const __hip_bfloat16* __restrict__ B,
    int K, int m0, int n0, int kchunks,
    __hip_bfloat16 (*As)[128 * 32], __hip_bfloat16 (*Bs)[128 * 32],
    floatx4 acc[4][4], floatx4 acc_s[4])
{
  const int tid  = threadIdx.x;
  const int lane = tid & 63;
  const int wave = tid >> 6;          // 0..3
  const int quad = lane >> 4;
  const int r    = lane & 15;
  const int wm   = (wave >> 1) * 64;
  const int wn   = (wave & 1) * 64;
  const int lrow = lane >> 2;         // 0..15
  const int lcol = (lane & 3) * 8;    // 0,8,16,24

  short8 ones;
#pragma unroll
  for (int t = 0; t < 8; ++t) ones[t] = (short)0x3F80;  // bf16 1.0

  const __hip_bfloat16* aB = A + (size_t)(m0 + wave * 32 + lrow) * K + lcol;
  const __hip_bfloat16* bB = B + (size_t)(n0 + wave * 32 + lrow) * K + lcol;

  // Prologue: stage tile 0.
#pragma unroll
  for (int s = 0; s < 2; ++s) {
    stage16(aB + (size_t)(16 * s) * K, As[0] + wave * 1024 + s * 512);
    stage16(bB + (size_t)(16 * s) * K, Bs[0] + wave * 1024 + s * 512);
  }
  asm volatile("s_waitcnt vmcnt(0)" ::: "memory");
  __builtin_amdgcn_sched_barrier(0);
  __builtin_amdgcn_s_barrier();

  for (int kt = 0; kt < kchunks; ++kt) {
    const int cur = kt & 1;
    if (kt + 1 < kchunks) {
      const int k0 = (kt + 1) * 32, nb = cur ^ 1;
#pragma unroll
      for (int s = 0; s < 2; ++s) {
        stage16(aB + (size_t)(16 * s) * K + k0, As[nb] + wave * 1024 + s * 512);
        stage16(bB + (size_t)(16 * s) * K + k0, Bs[nb] + wave * 1024 + s * 512);
      }
    }
    short8 a[4], bb[4];
#pragma unroll
    for (int i = 0; i < 4; ++i) {
      a[i]  = *(const short8*)(As[cur] + (wm + i * 16 + r) * 32 + quad * 8);
      bb[i] = *(const short8*)(Bs[cur] + (wn + i * 16 + r) * 32 + quad * 8);
    }
    if (SUMS) {
#pragma unroll
      for (int i = 0; i < 4; ++i)
        acc_s[i] = __builtin_amdgcn_mfma_f32_16x16x32_bf16(a[i], ones, acc_s[i], 0, 0, 0);
    }
#pragma unroll
    for (int i = 0; i < 4; ++i)
#pragma unroll
      for (int j = 0; j < 4; ++j)
        acc[i][j] = __builtin_amdgcn_mfma_f32_16x16x32_bf16(a[i], bb[j], acc[i][j], 0, 0, 0);
    STEP_FENCE();
  }
}

// ---------------------------------------------------------------------------
// Scores: P'[z][q][k] = exp((Q_z K_z^T)[q][k]/32) for k<=q (0 in the masked
// part of diagonal tiles), stored bf16. Q,K fp8 e4m3; BK=64 dbuf core.
// 128x128 tiles; 136 lower-tri tiles per batch; XCD-contiguous ordering.
// grid = (544), 256 threads, 32 KB LDS.
__global__ __launch_bounds__(256, 2) void gemm_scores(
    const unsigned char* __restrict__ Qb, const unsigned char* __restrict__ Kb,
    __hip_bfloat16* __restrict__ Sb)
{
  const int b    = blockIdx.x;                 // 0..543
  const int orig = (b & 7) * 68 + (b >> 3);    // 544 = 8*68, bijective
  const int z    = orig / 136;
  const int L    = orig - z * 136;
  int mt = (int)((sqrtf(8.0f * (float)L + 1.0f) - 1.0f) * 0.5f);
  while ((mt + 1) * (mt + 2) / 2 <= L) ++mt;
  while (mt * (mt + 1) / 2 > L) --mt;
  const int nt = L - mt * (mt + 1) / 2;
  const int m0 = mt * 128, n0 = nt * 128;

  __shared__ __align__(16) unsigned char As[2][128 * 64];
  __shared__ __align__(16) unsigned char Bs[2][128 * 64];
  const unsigned char* A = Qb + (size_t)z * SEQ * DMODEL;
  const unsigned char* B = Kb + (size_t)z * SEQ * DMODEL;
  __hip_bfloat16* outp = Sb + (size_t)z * SEQ * SEQ;
  floatx4 acc[4][4] = {};
  gemm_core_4w_fp8_db(A, B, DMODEL, m0, n0, DMODEL / 64, As, Bs, acc);

  const int lane = threadIdx.x & 63, wave = threadIdx.x >> 6;
  const int quad = lane >> 4, r = lane & 15;
  const int wm = (wave >> 1) * 64, wn = (wave & 1) * 64;
  const float scale = 0.03125f;  // 1/sqrt(1024)
#pragma unroll
  for (int i = 0; i < 4; ++i) {
    const int mbase = m0 + wm + i * 16 + quad * 4;
#pragma unroll
    for (int e = 0; e < 4; ++e) {
      const int row = mbase + e;
#pragma unroll
      for (int j = 0; j < 4; ++j) {
        const int n = n0 + wn + j * 16 + r;
        const float pv = (n <= row) ? __expf(acc[i][j][e] * scale) : 0.f;
        outp[(size_t)row * SEQ + n] = __float2bfloat16(pv);
      }
    }
  }
}

// ---------------------------------------------------------------------------
// PV: Out[z][q][d] = (P'_z @ Vt_z^T)[q][d] / rowsum(P'), fp32 out.
// Row sums via the ones-MFMA. 128x128 tiles, bf16 BK=32 dbuf core; K
// truncated at the diagonal.
// R21 2-D XCD tiling: XCD x = (z<<1)|nhalf owns {all mt 0..15} x {4 n-blocks
// of one n-half} for batch z. Per-XCD L2 working set = 4 Vt panels (2MB) +
// current Sb panel (<=0.5MB) -> Vt read from L2 by 16 mt-blocks (B traffic
// 143->~16MB), Sb fetched once per n-half (~36MB). Balance exact: every XCD
// carries the same mt distribution; mt descending (longest-first); same-mt
// blocks consecutive (share the Sb panel).
// grid = (512), 256 threads, 32 KB LDS.
__global__ __launch_bounds__(256, 2) void gemm_pv(
    const __hip_bfloat16* __restrict__ Sb, const __hip_bfloat16* __restrict__ Vt,
    float* __restrict__ Out)
{
  const int b     = blockIdx.x;    // 0..511
  const int xcd   = b & 7;
  const int s     = b >> 3;        // issue slot within XCD, 0..63
  const int z     = xcd >> 1;      // batch: 2 XCDs per batch
  const int nhalf = xcd & 1;       // n-half: d-cols [nhalf*512, nhalf*512+512)
  const int mt    = 15 - (s >> 2); // slot 0 -> mt=15 (longest K first)
  const int n0    = (nhalf * 4 + (s & 3)) * 128;
  const int m0    = mt * 128;

  __shared__ __align__(16) __hip_bfloat16 As[2][128 * 32];
  __shared__ __align__(16) __hip_bfloat16 Bs[2][128 * 32];
  const __hip_bfloat16* A = Sb + (size_t)z * SEQ * SEQ;
  const __hip_bfloat16* B = Vt + (size_t)z * DMODEL * SEQ;
  float* outp = Out + (size_t)z * SEQ * DMODEL;

  floatx4 acc[4][4] = {};
  floatx4 acc_s[4] = {};
  const int kchunks = 4 * mt + 4;   // (m0+128)/32: causal truncation
  gemm_core_4w_db<true>(A, B, SEQ, m0, n0, kchunks, As, Bs, acc, acc_s);

  const int lane = threadIdx.x & 63, wave = threadIdx.x >> 6;
  const int quad = lane >> 4, r = lane & 15;
  const int wm = (wave >> 1) * 64, wn = (wave & 1) * 64;
#pragma unroll
  for (int i = 0; i < 4; ++i) {
    const int mbase = m0 + wm + i * 16 + quad * 4;
    float inv[4];
#pragma unroll
    for (int e = 0; e < 4; ++e) inv[e] = 1.f / acc_s[i][e];
#pragma unroll
    for (int j = 0; j < 4; ++j) {
      const int n = n0 + wn + j * 16 + r;
#pragma unroll
      for (int e = 0; e < 4; ++e)
        outp[(size_t)(mbase + e) * DMODEL + n] = acc[i][j][e] * inv[e];
    }
  }
}

// ---------------------------------------------------------------------------
extern "C" void kernel_launch(void* const* d_in, const int* in_sizes, int n_in,
                              void* d_out, int out_size, void* d_ws, size_t ws_size,
                              hipStream_t stream)
{
  const float* X  = (const float*)d_in[0];
  const float* Wq = (const float*)d_in[1];
  const float* bq = (const float*)d_in[2];
  const float* Wk = (const float*)d_in[3];
  const float* bk = (const float*)d_in[4];
  const float* Wv = (const float*)d_in[5];
  const float* bv = (const float*)d_in[6];
  float* Out = (float*)d_out;

  // Workspace layout (~87 MB total)
  char* ws = (char*)d_ws;
  size_t off = 0;
  auto alloc = [&](size_t bytes) -> void* {
    void* p = ws + off;
    off += (bytes + 255) & ~(size_t)255;
    return p;
  };
  __hip_bfloat16* Xb  = (__hip_bfloat16*)alloc((size_t)MTOT * DMODEL * 2);    // 16 MB
  __hip_bfloat16* Wqb = (__hip_bfloat16*)alloc((size_t)DMODEL * DMODEL * 2);  // 2 MB
  __hip_bfloat16* Wkb = (__hip_bfloat16*)alloc((size_t)DMODEL * DMODEL * 2);
  __hip_bfloat16* Wvb = (__hip_bfloat16*)alloc((size_t)DMODEL * DMODEL * 2);
  unsigned char*  Qb  = (unsigned char*)alloc((size_t)MTOT * DMODEL);         // 8 MB (fp8)
  unsigned char*  Kb  = (unsigned char*)alloc((size_t)MTOT * DMODEL);         // 8 MB (fp8)
  __hip_bfloat16* Vt  = (__hip_bfloat16*)alloc((size_t)MTOT * DMODEL * 2);    // 16 MB
  __hip_bfloat16* Sb  = (__hip_bfloat16*)alloc((size_t)NBATCH * SEQ * SEQ * 2); // 32 MB
  (void)ws_size; (void)in_sizes; (void)n_in; (void)out_size;

  // 1) converts (one kernel)
  convert_all<<<11264, 256, 0, stream>>>(X, Wq, Wk, Wv, Xb, Wqb, Wkb, Wvb);
  // 2) fused QKV projection, prefetch-1 dbuf; Q,K fp8 e4m3, V -> Vt
  gemm_qkv_db<<<512, 256, 0, stream>>>(
      Xb, Wqb, Wkb, Wvb, bq, bk, bv, Qb, Kb, Vt);
  // 3) scores: fp8 BK=64 dbuf core, tri-compact + XCD-contiguous
  gemm_scores<<<dim3(544), 256, 0, stream>>>(Qb, Kb, Sb);
  // 4) PV: bf16 dbuf core, 2-D XCD tiling (Vt L2-resident), longest-first
  gemm_pv<<<dim3(512), 256, 0, stream>>>(Sb, Vt, Out);
}

// Round 11
// 214.368 us; speedup vs baseline: 1.0300x; 1.0300x over previous
//
#include <hip/hip_runtime.h>
#include <hip/hip_bf16.h>
#include <hip/hip_fp8.h>

// Self-attention: q=X@Wq.T+bq, k=..., v=...; S = causal_softmax(q k^T / 32); O = S v
// B=4, S=2048, D_IN=D_OUT=1024. fp32 in/out; internal bf16/fp8 MFMA + fp32 acc.
//
// R24 = R22 resubmitted verbatim (R22/R23 benches failed on GPU acquisition).
// R22 consolidation (post-mortem of R20/R21): cross-round ledger shows the
// dbuf+STEP_FENCE transform HELPED the long-block qkv (64.8->60.6) but HURT
// the 2-blk/CU scores+pv pair (R14 rest=131 -> R20/21 rest=144-149): their
// inter-block wave overlap already absorbed the staging drain, and the dbuf
// added a ~900cy serial prologue (dominant for pv's short mt blocks) plus
// sched_barrier pins. pv XCD remaps were neutral: all 512 pv blocks are
// CO-RESIDENT (2/CU), so issue-order-based locality reasoning was invalid.
// => assemble best-measured components:
//   - qkv:    R20 gemm_qkv_db (measured 60.6us, MfmaUtil 34%, FETCH 33MB).
//   - scores: R14 4-wave fp8 BK=64 single-buffer __syncthreads core (16KB).
//   - pv:     R14 4-wave bf16 BK=32 single-buffer core + ones-MFMA sums.
//   - convert unchanged.
//
// MFMA fragment layouts (HW-verified per guide §3):
//  A: lane holds A[m=lane&15][k=(lane>>4)*8+j], j=0..7
//  B: lane holds B[k=(lane>>4)*8+j][n=lane&15]
//  C/D: lane holds D[row=(lane>>4)*4+e][col=lane&15], e=0..3

typedef __attribute__((ext_vector_type(8))) short short8;   // 8 bf16 = 4 VGPRs
typedef __attribute__((ext_vector_type(4))) float floatx4;  // MFMA acc
typedef __attribute__((ext_vector_type(2))) long longx2;    // 16B = 2 fp8 frags

#define SEQ   2048
#define DMODEL 1024
#define NBATCH 4
#define MTOT  (SEQ * NBATCH)

// End-of-step fence for the qkv dbuf core.
#define STEP_FENCE() do {                                              \
    asm volatile("s_waitcnt vmcnt(0) lgkmcnt(0)" ::: "memory");        \
    __builtin_amdgcn_sched_barrier(0);                                 \
    __builtin_amdgcn_s_barrier(); } while (0)

// Direct global->LDS async copy, 16B per lane. LDS dst is wave-uniform base +
// lane*16 (per-lane scatter NOT supported).
__device__ __forceinline__ void stage16(const void* g, void* l)
{
  __builtin_amdgcn_global_load_lds(
      (const __attribute__((address_space(1))) void*)g,
      (__attribute__((address_space(3))) void*)l, 16, 0, 0);
}

__device__ __forceinline__ unsigned short bf16_bits(float f)
{
  __hip_bfloat16 h = __float2bfloat16(f);
  return *(unsigned short*)&h;
}

__device__ __forceinline__ unsigned char fp8_bits(float f)
{
  __hip_fp8_e4m3 h(f);            // OCP e4m3 (gfx950), not fnuz
  return h.__x;
}

// ---------------------------------------------------------------------------
// One-kernel fp32 -> bf16 convert for all four inputs. Each block: 1024 elems.
__global__ __launch_bounds__(256) void convert_all(
    const float* __restrict__ X,  const float* __restrict__ Wq,
    const float* __restrict__ Wk, const float* __restrict__ Wv,
    __hip_bfloat16* __restrict__ Xb,  __hip_bfloat16* __restrict__ Wqb,
    __hip_bfloat16* __restrict__ Wkb, __hip_bfloat16* __restrict__ Wvb)
{
  const int b = blockIdx.x;
  const float* src; __hip_bfloat16* dst; int rel;
  if (b < 8192)       { src = X;  dst = Xb;  rel = b; }
  else if (b < 9216)  { src = Wq; dst = Wqb; rel = b - 8192; }
  else if (b < 10240) { src = Wk; dst = Wkb; rel = b - 9216; }
  else                { src = Wv; dst = Wvb; rel = b - 10240; }
  const int i = rel * 1024 + threadIdx.x * 4;
  float4 f = *(const float4*)(src + i);
  uint2 o;
  o.x = (unsigned)bf16_bits(f.x) | ((unsigned)bf16_bits(f.y) << 16);
  o.y = (unsigned)bf16_bits(f.z) | ((unsigned)bf16_bits(f.w) << 16);
  *(uint2*)(dst + i) = o;
}

// ---------------------------------------------------------------------------
// Fused QKV projection, prefetch-1 double-buffered (measured 60.6us, R20).
// 4 waves, tile 128(m) x 128(n) x {Q,K,V}, BK=32, 48 MFMA/wave/step between
// single barriers. LDS 2 x (8+24) = 64 KB. Q,K stored fp8 e4m3 row-major;
// V stored bf16 transposed to Vt. grid = 512 flat (XCD-chunked, mt-grouped),
// 256 threads.
__global__ __launch_bounds__(256, 2) void gemm_qkv_db(
    const __hip_bfloat16* __restrict__ Xb,
    const __hip_bfloat16* __restrict__ Wqb,
    const __hip_bfloat16* __restrict__ Wkb,
    const __hip_bfloat16* __restrict__ Wvb,
    const float* __restrict__ bq, const float* __restrict__ bk, const float* __restrict__ bv,
    unsigned char* __restrict__ Qb, unsigned char* __restrict__ Kb,
    __hip_bfloat16* __restrict__ Vt)
{
  __shared__ __hip_bfloat16 As[2][128 * 32];      // 2 x 8 KB
  __shared__ __hip_bfloat16 Bs[2][3][128 * 32];   // 2 x 24 KB

  // XCD-chunked bijective swizzle (512 % 8 == 0), mt-grouped.
  const int b    = blockIdx.x;                 // 0..511
  const int orig = (b & 7) * 64 + (b >> 3);
  const int mt = orig >> 3, ng = orig & 7;
  const int m0 = mt * 128, n0 = ng * 128;

  const int tid  = threadIdx.x;
  const int lane = tid & 63;
  const int wave = tid >> 6;                   // 0..3
  const int quad = lane >> 4;
  const int r    = lane & 15;
  const int wm   = (wave >> 1) * 64;
  const int wn   = (wave & 1) * 64;
  const int srow = wave * 16 + (lane >> 2);    // 0..63
  const int scol = (lane & 3) * 8;             // 0,8,16,24

  const __hip_bfloat16* aR0 = Xb + (size_t)(m0 + srow) * DMODEL + scol;
  const __hip_bfloat16* aR1 = aR0 + (size_t)64 * DMODEL;
  const __hip_bfloat16* bR0[3], * bR1[3];
  {
    const __hip_bfloat16* Wp[3] = {Wqb, Wkb, Wvb};
#pragma unroll
    for (int w = 0; w < 3; ++w) {
      bR0[w] = Wp[w] + (size_t)(n0 + srow) * DMODEL + scol;
      bR1[w] = bR0[w] + (size_t)64 * DMODEL;
    }
  }

  floatx4 acc[3][4][4] = {};

  // Prologue: stage K-tile 0 into buffer 0, wait, publish.
  {
    stage16(aR0, As[0] + wave * 512);
    stage16(aR1, As[0] + 2048 + wave * 512);
#pragma unroll
    for (int w = 0; w < 3; ++w) {
      stage16(bR0[w], Bs[0][w] + wave * 512);
      stage16(bR1[w], Bs[0][w] + 2048 + wave * 512);
    }
    asm volatile("s_waitcnt vmcnt(0)" ::: "memory");
    __builtin_amdgcn_sched_barrier(0);
    __builtin_amdgcn_s_barrier();
  }

  for (int kt = 0; kt < 32; ++kt) {
    const int cur = kt & 1;
    // Issue next tile's staging FIRST (hides under this tile's compute).
    if (kt < 31) {
      const int k0 = (kt + 1) * 32, nb = cur ^ 1;
      stage16(aR0 + k0, As[nb] + wave * 512);
      stage16(aR1 + k0, As[nb] + 2048 + wave * 512);
#pragma unroll
      for (int w = 0; w < 3; ++w) {
        stage16(bR0[w] + k0, Bs[nb][w] + wave * 512);
        stage16(bR1[w] + k0, Bs[nb][w] + 2048 + wave * 512);
      }
    }
    // Compute current tile: 16 ds_read_b128 + 48 MFMA.
    short8 a[4];
#pragma unroll
    for (int i = 0; i < 4; ++i)
      a[i] = *(const short8*)(As[cur] + (wm + i * 16 + r) * 32 + quad * 8);
#pragma unroll
    for (int w = 0; w < 3; ++w) {
      short8 bb[4];
#pragma unroll
      for (int j = 0; j < 4; ++j)
        bb[j] = *(const short8*)(Bs[cur][w] + (wn + j * 16 + r) * 32 + quad * 8);
#pragma unroll
      for (int i = 0; i < 4; ++i)
#pragma unroll
        for (int j = 0; j < 4; ++j)
          acc[w][i][j] = __builtin_amdgcn_mfma_f32_16x16x32_bf16(a[i], bb[j], acc[w][i][j], 0, 0, 0);
    }
    STEP_FENCE();   // next tile landed (issued ~450 cyc ago) + my reads done
  }

  // Q, K: fp8 e4m3 row-major stores
  {
    unsigned char* Op[2] = {Qb, Kb};
    const float* Bp[2] = {bq, bk};
#pragma unroll
    for (int w = 0; w < 2; ++w) {
      unsigned char* out = Op[w];
#pragma unroll
      for (int j = 0; j < 4; ++j) {
        const int n = n0 + wn + j * 16 + r;
        const float bb = Bp[w][n];
#pragma unroll
        for (int i = 0; i < 4; ++i) {
          const int mbase = m0 + wm + i * 16 + quad * 4;
#pragma unroll
          for (int e = 0; e < 4; ++e)
            out[(size_t)(mbase + e) * DMODEL + n] = fp8_bits(acc[w][i][j][e] + bb);
        }
      }
    }
  }
  // V: transposed bf16 store Vt[z][d=n][pos], 8B packed per (i,j).
  {
    const int z    = m0 >> 11;           // SEQ = 2048
    const int posb = (m0 & (SEQ - 1)) + wm;
    __hip_bfloat16* vt = Vt + (size_t)z * DMODEL * SEQ;
#pragma unroll
    for (int j = 0; j < 4; ++j) {
      const int n = n0 + wn + j * 16 + r;
      const float bb = bv[n];
#pragma unroll
      for (int i = 0; i < 4; ++i) {
        const int pos = posb + i * 16 + quad * 4;
        unsigned long long pk =
            (unsigned long long)bf16_bits(acc[2][i][j][0] + bb)
          | ((unsigned long long)bf16_bits(acc[2][i][j][1] + bb) << 16)
          | ((unsigned long long)bf16_bits(acc[2][i][j][2] + bb) << 32)
          | ((unsigned long long)bf16_bits(acc[2][i][j][3] + bb) << 48);
        *(unsigned long long*)(vt + (size_t)n * SEQ + pos) = pk;
      }
    }
  }
}

// ---------------------------------------------------------------------------
// 4-wave fp8 GEMM core (R14, single-buffer 2-barrier): C[128x128] += A * B^T,
// A/B e4m3 row-major [.,K], BK=64. 16 KB LDS. Each 16B register pair = 2 fp8
// A/B-frags (kk=0,1) -> 32 MFMA/wave/barrier. k within a 16B group is
// permuted vs native MFMA order — consistent for A and B, so exact.
__device__ __forceinline__ void gemm_core_4w_fp8(
    const unsigned char* __restrict__ A,
    const unsigned char* __restrict__ B,
    int K, int m0, int n0, int kchunks,
    unsigned char* As /*128x64B*/, unsigned char* Bs /*128x64B*/,
    floatx4 acc[4][4])
{
  const int tid  = threadIdx.x;
  const int lane = tid & 63;
  const int wave = tid >> 6;          // 0..3
  const int quad = lane >> 4;
  const int r    = lane & 15;
  const int wm   = (wave >> 1) * 64;
  const int wn   = (wave & 1) * 64;
  const int lrow = lane >> 2;         // 0..15
  const int lcol = (lane & 3) * 16;   // byte col 0,16,32,48

  const unsigned char* aB = A + (size_t)(m0 + wave * 32 + lrow) * K + lcol;
  const unsigned char* bB = B + (size_t)(n0 + wave * 32 + lrow) * K + lcol;
  unsigned char* lA = As + wave * 2048;   // 2 chunks of 1024 B
  unsigned char* lB = Bs + wave * 2048;

  for (int kt = 0; kt < kchunks; ++kt) {
    const int k0 = kt * 64;
#pragma unroll
    for (int s = 0; s < 2; ++s) {
      stage16(aB + (size_t)(16 * s) * K + k0, lA + s * 1024);
      stage16(bB + (size_t)(16 * s) * K + k0, lB + s * 1024);
    }
    __syncthreads();
    longx2 a[4], b[4];
#pragma unroll
    for (int i = 0; i < 4; ++i) {
      a[i] = __builtin_bit_cast(longx2, *(const int4*)(As + (wm + i * 16 + r) * 64 + quad * 16));
      b[i] = __builtin_bit_cast(longx2, *(const int4*)(Bs + (wn + i * 16 + r) * 64 + quad * 16));
    }
#pragma unroll
    for (int kk = 0; kk < 2; ++kk)
#pragma unroll
      for (int i = 0; i < 4; ++i)
#pragma unroll
        for (int j = 0; j < 4; ++j)
          acc[i][j] = __builtin_amdgcn_mfma_f32_16x16x32_fp8_fp8(
              a[i][kk], b[j][kk], acc[i][j], 0, 0, 0);
    __syncthreads();
  }
}

// ---------------------------------------------------------------------------
// 4-wave bf16 GEMM core (R14, single-buffer 2-barrier): C[128x128] += A * B^T,
// BK=32, 16 KB LDS. If SUMS: acc_s[i] += A-frag x ones (row sums of A).
template <bool SUMS>
__device__ __forceinline__ void gemm_core_4w(
    const __hip_bfloat16* __restrict__ A,
    const __hip_bfloat16* __restrict__ B,
    int K, int m0, int n0, int kchunks,
    __hip_bfloat16* As /*128x32*/, __hip_bfloat16* Bs /*128x32*/,
    floatx4 acc[4][4], floatx4 acc_s[4])
{
  const int tid  = threadIdx.x;
  const int lane = tid & 63;
  const int wave = tid >> 6;          // 0..3
  const int quad = lane >> 4;
  const int r    = lane & 15;
  const int wm   = (wave >> 1) * 64;
  const int wn   = (wave & 1) * 64;
  const int lrow = lane >> 2;         // 0..15
  const int lcol = (lane & 3) * 8;    // 0,8,16,24

  short8 ones;
#pragma unroll
  for (int t = 0; t < 8; ++t) ones[t] = (short)0x3F80;  // bf16 1.0

  const __hip_bfloat16* aB = A + (size_t)(m0 + wave * 32 + lrow) * K + lcol;
  const __hip_bfloat16* bB = B + (size_t)(n0 + wave * 32 + lrow) * K + lcol;
  __hip_bfloat16* lA = As + wave * 1024;   // 2 chunks of 512 elems
  __hip_bfloat16* lB = Bs + wave * 1024;

  for (int kt = 0; kt < kchunks; ++kt) {
    const int k0 = kt * 32;
#pragma unroll
    for (int s = 0; s < 2; ++s) {
      stage16(aB + (size_t)(16 * s) * K + k0, lA + s * 512);
      stage16(bB + (size_t)(16 * s) * K + k0, lB + s * 512);
    }
    __syncthreads();
    short8 a[4], b[4];
#pragma unroll
    for (int i = 0; i < 4; ++i) {
      a[i] = *(const short8*)(As + (wm + i * 16 + r) * 32 + quad * 8);
      b[i] = *(const short8*)(Bs + (wn + i * 16 + r) * 32 + quad * 8);
    }
    if (SUMS) {
#pragma unroll
      for (int i = 0; i < 4; ++i)
        acc_s[i] = __builtin_amdgcn_mfma_f32_16x16x32_bf16(a[i], ones, acc_s[i], 0, 0, 0);
    }
#pragma unroll
    for (int i = 0; i < 4; ++i)
#pragma unroll
      for (int j = 0; j < 4; ++j)
        acc[i][j] = __builtin_amdgcn_mfma_f32_16x16x32_bf16(a[i], b[j], acc[i][j], 0, 0, 0);
    __syncthreads();
  }
}

// ---------------------------------------------------------------------------
// Scores: P'[z][q][k] = exp((Q_z K_z^T)[q][k]/32) for k<=q (0 in the masked
// part of diagonal tiles), stored bf16. Q,K fp8 e4m3; BK=64 4-wave core.
// 128x128 tiles; 136 lower-tri tiles per batch, compact linear index.
// XCD-contiguous ordering. grid = (544), 256 threads, 16 KB LDS.
__global__ __launch_bounds__(256, 2) void gemm_scores(
    const unsigned char* __restrict__ Qb, const unsigned char* __restrict__ Kb,
    __hip_bfloat16* __restrict__ Sb)
{
  const int b    = blockIdx.x;                 // 0..543
  const int orig = (b & 7) * 68 + (b >> 3);    // 544 = 8*68, bijective
  const int z    = orig / 136;
  const int L    = orig - z * 136;
  int mt = (int)((sqrtf(8.0f * (float)L + 1.0f) - 1.0f) * 0.5f);
  while ((mt + 1) * (mt + 2) / 2 <= L) ++mt;
  while (mt * (mt + 1) / 2 > L) --mt;
  const int nt = L - mt * (mt + 1) / 2;
  const int m0 = mt * 128, n0 = nt * 128;

  __shared__ __align__(16) unsigned char As[128 * 64];
  __shared__ __align__(16) unsigned char Bs[128 * 64];
  const unsigned char* A = Qb + (size_t)z * SEQ * DMODEL;
  const unsigned char* B = Kb + (size_t)z * SEQ * DMODEL;
  __hip_bfloat16* outp = Sb + (size_t)z * SEQ * SEQ;
  floatx4 acc[4][4] = {};
  gemm_core_4w_fp8(A, B, DMODEL, m0, n0, DMODEL / 64, As, Bs, acc);

  const int lane = threadIdx.x & 63, wave = threadIdx.x >> 6;
  const int quad = lane >> 4, r = lane & 15;
  const int wm = (wave >> 1) * 64, wn = (wave & 1) * 64;
  const float scale = 0.03125f;  // 1/sqrt(1024)
#pragma unroll
  for (int i = 0; i < 4; ++i) {
    const int mbase = m0 + wm + i * 16 + quad * 4;
#pragma unroll
    for (int e = 0; e < 4; ++e) {
      const int row = mbase + e;
#pragma unroll
      for (int j = 0; j < 4; ++j) {
        const int n = n0 + wn + j * 16 + r;
        const float pv = (n <= row) ? __expf(acc[i][j][e] * scale) : 0.f;
        outp[(size_t)row * SEQ + n] = __float2bfloat16(pv);
      }
    }
  }
}

// ---------------------------------------------------------------------------
// PV: Out[z][q][d] = (P'_z @ Vt_z^T)[q][d] / rowsum(P'), fp32 out.
// Row sums via the ones-MFMA. 128x128 tiles, bf16 BK=32 4-wave core; K
// truncated at the diagonal. R14 decode: (z,mt) groups of 8 n-blocks dealt
// to XCDs round-robin by descending K. grid = (512), 256 threads, 16 KB LDS.
__global__ __launch_bounds__(256, 2) void gemm_pv(
    const __hip_bfloat16* __restrict__ Sb, const __hip_bfloat16* __restrict__ Vt,
    float* __restrict__ Out)
{
  const int b    = blockIdx.x;     // 0..511
  const int xcd  = b & 7;
  const int slot = b >> 3;         // 0..63 within XCD
  const int gi   = slot >> 3;      // group index within XCD, 0..7
  const int q    = gi * 8 + xcd;   // global group rank, 0..63 (descending K)
  const int n0   = (slot & 7) * 128;
  const int z    = q & 3;
  const int mt   = 15 - (q >> 2);  // rank 0 -> mt=15 (longest K)
  const int m0   = mt * 128;

  __shared__ __align__(16) __hip_bfloat16 As[128 * 32];
  __shared__ __align__(16) __hip_bfloat16 Bs[128 * 32];
  const __hip_bfloat16* A = Sb + (size_t)z * SEQ * SEQ;
  const __hip_bfloat16* B = Vt + (size_t)z * DMODEL * SEQ;
  float* outp = Out + (size_t)z * SEQ * DMODEL;

  floatx4 acc[4][4] = {};
  floatx4 acc_s[4] = {};
  const int kchunks = 4 * mt + 4;   // (m0+128)/32: causal truncation
  gemm_core_4w<true>(A, B, SEQ, m0, n0, kchunks, As, Bs, acc, acc_s);

  const int lane = threadIdx.x & 63, wave = threadIdx.x >> 6;
  const int quad = lane >> 4, r = lane & 15;
  const int wm = (wave >> 1) * 64, wn = (wave & 1) * 64;
#pragma unroll
  for (int i = 0; i < 4; ++i) {
    const int mbase = m0 + wm + i * 16 + quad * 4;
    float inv[4];
#pragma unroll
    for (int e = 0; e < 4; ++e) inv[e] = 1.f / acc_s[i][e];
#pragma unroll
    for (int j = 0; j < 4; ++j) {
      const int n = n0 + wn + j * 16 + r;
#pragma unroll
      for (int e = 0; e < 4; ++e)
        outp[(size_t)(mbase + e) * DMODEL + n] = acc[i][j][e] * inv[e];
    }
  }
}

// ---------------------------------------------------------------------------
extern "C" void kernel_launch(void* const* d_in, const int* in_sizes, int n_in,
                              void* d_out, int out_size, void* d_ws, size_t ws_size,
                              hipStream_t stream)
{
  const float* X  = (const float*)d_in[0];
  const float* Wq = (const float*)d_in[1];
  const float* bq = (const float*)d_in[2];
  const float* Wk = (const float*)d_in[3];
  const float* bk = (const float*)d_in[4];
  const float* Wv = (const float*)d_in[5];
  const float* bv = (const float*)d_in[6];
  float* Out = (float*)d_out;

  // Workspace layout (~87 MB total)
  char* ws = (char*)d_ws;
  size_t off = 0;
  auto alloc = [&](size_t bytes) -> void* {
    void* p = ws + off;
    off += (bytes + 255) & ~(size_t)255;
    return p;
  };
  __hip_bfloat16* Xb  = (__hip_bfloat16*)alloc((size_t)MTOT * DMODEL * 2);    // 16 MB
  __hip_bfloat16* Wqb = (__hip_bfloat16*)alloc((size_t)DMODEL * DMODEL * 2);  // 2 MB
  __hip_bfloat16* Wkb = (__hip_bfloat16*)alloc((size_t)DMODEL * DMODEL * 2);
  __hip_bfloat16* Wvb = (__hip_bfloat16*)alloc((size_t)DMODEL * DMODEL * 2);
  unsigned char*  Qb  = (unsigned char*)alloc((size_t)MTOT * DMODEL);         // 8 MB (fp8)
  unsigned char*  Kb  = (unsigned char*)alloc((size_t)MTOT * DMODEL);         // 8 MB (fp8)
  __hip_bfloat16* Vt  = (__hip_bfloat16*)alloc((size_t)MTOT * DMODEL * 2);    // 16 MB
  __hip_bfloat16* Sb  = (__hip_bfloat16*)alloc((size_t)NBATCH * SEQ * SEQ * 2); // 32 MB
  (void)ws_size; (void)in_sizes; (void)n_in; (void)out_size;

  // 1) converts (one kernel)
  convert_all<<<11264, 256, 0, stream>>>(X, Wq, Wk, Wv, Xb, Wqb, Wkb, Wvb);
  // 2) fused QKV projection, prefetch-1 dbuf (R20 measured 60.6us)
  gemm_qkv_db<<<512, 256, 0, stream>>>(
      Xb, Wqb, Wkb, Wvb, bq, bk, bv, Qb, Kb, Vt);
  // 3) scores: R14 single-buffer fp8 BK=64 core, tri-compact + XCD swizzle
  gemm_scores<<<dim3(544), 256, 0, stream>>>(Qb, Kb, Sb);
  // 4) PV: R14 single-buffer bf16 core, XCD deal, row sums + normalize
  gemm_pv<<<dim3(512), 256, 0, stream>>>(Sb, Vt, Out);
}

// Round 13
// 213.961 us; speedup vs baseline: 1.0319x; 1.0019x over previous
//
#include <hip/hip_runtime.h>
#include <hip/hip_bf16.h>
#include <hip/hip_fp8.h>

// Self-attention: q=X@Wq.T+bq, k=..., v=...; S = causal_softmax(q k^T / 32); O = S v
// B=4, S=2048, D_IN=D_OUT=1024. fp32 in/out; internal bf16/fp8 MFMA + fp32 acc.
//
// R26 = R25 resubmitted verbatim (R25 bench failed on GPU acquisition).
// R25 change (single, contained): pv per-CU load balancing. R22/R24 measured
// 214.4us; rest(scores+pv) ~143 regardless of buffering (R20/21/24 all agree;
// R14's "131" was cross-round noise). pv's blocks are ALL co-resident (2/CU);
// under linear CU fill (CU c hosts slots c and c+32), the old descending-mt
// deal paired (mt15+mt7)=96 kchunks on CU0 vs (mt9+mt1)=48 on CU31 — 2:1
// spread, makespan set by the 96s. New rank->gi map {0,1,2,3,7,6,5,4} pairs
// (mt15,mt1)(mt13,mt3)(mt11,mt5)(mt9,mt7): EXACTLY equal (72 units) on every
// CU of odd-mt XCDs, 64 on even-mt XCDs. Worst case (different fill model):
// neutral. qkv / scores / convert byte-identical to R24 (214.4us measured).
//
// MFMA fragment layouts (HW-verified per guide §3):
//  A: lane holds A[m=lane&15][k=(lane>>4)*8+j], j=0..7
//  B: lane holds B[k=(lane>>4)*8+j][n=lane&15]
//  C/D: lane holds D[row=(lane>>4)*4+e][col=lane&15], e=0..3

typedef __attribute__((ext_vector_type(8))) short short8;   // 8 bf16 = 4 VGPRs
typedef __attribute__((ext_vector_type(4))) float floatx4;  // MFMA acc
typedef __attribute__((ext_vector_type(2))) long longx2;    // 16B = 2 fp8 frags

#define SEQ   2048
#define DMODEL 1024
#define NBATCH 4
#define MTOT  (SEQ * NBATCH)

// End-of-step fence for the qkv dbuf core.
#define STEP_FENCE() do {                                              \
    asm volatile("s_waitcnt vmcnt(0) lgkmcnt(0)" ::: "memory");        \
    __builtin_amdgcn_sched_barrier(0);                                 \
    __builtin_amdgcn_s_barrier(); } while (0)

// Direct global->LDS async copy, 16B per lane. LDS dst is wave-uniform base +
// lane*16 (per-lane scatter NOT supported).
__device__ __forceinline__ void stage16(const void* g, void* l)
{
  __builtin_amdgcn_global_load_lds(
      (const __attribute__((address_space(1))) void*)g,
      (__attribute__((address_space(3))) void*)l, 16, 0, 0);
}

__device__ __forceinline__ unsigned short bf16_bits(float f)
{
  __hip_bfloat16 h = __float2bfloat16(f);
  return *(unsigned short*)&h;
}

__device__ __forceinline__ unsigned char fp8_bits(float f)
{
  __hip_fp8_e4m3 h(f);            // OCP e4m3 (gfx950), not fnuz
  return h.__x;
}

// ---------------------------------------------------------------------------
// One-kernel fp32 -> bf16 convert for all four inputs. Each block: 1024 elems.
__global__ __launch_bounds__(256) void convert_all(
    const float* __restrict__ X,  const float* __restrict__ Wq,
    const float* __restrict__ Wk, const float* __restrict__ Wv,
    __hip_bfloat16* __restrict__ Xb,  __hip_bfloat16* __restrict__ Wqb,
    __hip_bfloat16* __restrict__ Wkb, __hip_bfloat16* __restrict__ Wvb)
{
  const int b = blockIdx.x;
  const float* src; __hip_bfloat16* dst; int rel;
  if (b < 8192)       { src = X;  dst = Xb;  rel = b; }
  else if (b < 9216)  { src = Wq; dst = Wqb; rel = b - 8192; }
  else if (b < 10240) { src = Wk; dst = Wkb; rel = b - 9216; }
  else                { src = Wv; dst = Wvb; rel = b - 10240; }
  const int i = rel * 1024 + threadIdx.x * 4;
  float4 f = *(const float4*)(src + i);
  uint2 o;
  o.x = (unsigned)bf16_bits(f.x) | ((unsigned)bf16_bits(f.y) << 16);
  o.y = (unsigned)bf16_bits(f.z) | ((unsigned)bf16_bits(f.w) << 16);
  *(uint2*)(dst + i) = o;
}

// ---------------------------------------------------------------------------
// Fused QKV projection, prefetch-1 double-buffered (measured 60.6us, R20).
// 4 waves, tile 128(m) x 128(n) x {Q,K,V}, BK=32, 48 MFMA/wave/step between
// single barriers. LDS 2 x (8+24) = 64 KB. Q,K stored fp8 e4m3 row-major;
// V stored bf16 transposed to Vt. grid = 512 flat (XCD-chunked, mt-grouped),
// 256 threads.
__global__ __launch_bounds__(256, 2) void gemm_qkv_db(
    const __hip_bfloat16* __restrict__ Xb,
    const __hip_bfloat16* __restrict__ Wqb,
    const __hip_bfloat16* __restrict__ Wkb,
    const __hip_bfloat16* __restrict__ Wvb,
    const float* __restrict__ bq, const float* __restrict__ bk, const float* __restrict__ bv,
    unsigned char* __restrict__ Qb, unsigned char* __restrict__ Kb,
    __hip_bfloat16* __restrict__ Vt)
{
  __shared__ __hip_bfloat16 As[2][128 * 32];      // 2 x 8 KB
  __shared__ __hip_bfloat16 Bs[2][3][128 * 32];   // 2 x 24 KB

  // XCD-chunked bijective swizzle (512 % 8 == 0), mt-grouped.
  const int b    = blockIdx.x;                 // 0..511
  const int orig = (b & 7) * 64 + (b >> 3);
  const int mt = orig >> 3, ng = orig & 7;
  const int m0 = mt * 128, n0 = ng * 128;

  const int tid  = threadIdx.x;
  const int lane = tid & 63;
  const int wave = tid >> 6;                   // 0..3
  const int quad = lane >> 4;
  const int r    = lane & 15;
  const int wm   = (wave >> 1) * 64;
  const int wn   = (wave & 1) * 64;
  const int srow = wave * 16 + (lane >> 2);    // 0..63
  const int scol = (lane & 3) * 8;             // 0,8,16,24

  const __hip_bfloat16* aR0 = Xb + (size_t)(m0 + srow) * DMODEL + scol;
  const __hip_bfloat16* aR1 = aR0 + (size_t)64 * DMODEL;
  const __hip_bfloat16* bR0[3], * bR1[3];
  {
    const __hip_bfloat16* Wp[3] = {Wqb, Wkb, Wvb};
#pragma unroll
    for (int w = 0; w < 3; ++w) {
      bR0[w] = Wp[w] + (size_t)(n0 + srow) * DMODEL + scol;
      bR1[w] = bR0[w] + (size_t)64 * DMODEL;
    }
  }

  floatx4 acc[3][4][4] = {};

  // Prologue: stage K-tile 0 into buffer 0, wait, publish.
  {
    stage16(aR0, As[0] + wave * 512);
    stage16(aR1, As[0] + 2048 + wave * 512);
#pragma unroll
    for (int w = 0; w < 3; ++w) {
      stage16(bR0[w], Bs[0][w] + wave * 512);
      stage16(bR1[w], Bs[0][w] + 2048 + wave * 512);
    }
    asm volatile("s_waitcnt vmcnt(0)" ::: "memory");
    __builtin_amdgcn_sched_barrier(0);
    __builtin_amdgcn_s_barrier();
  }

  for (int kt = 0; kt < 32; ++kt) {
    const int cur = kt & 1;
    // Issue next tile's staging FIRST (hides under this tile's compute).
    if (kt < 31) {
      const int k0 = (kt + 1) * 32, nb = cur ^ 1;
      stage16(aR0 + k0, As[nb] + wave * 512);
      stage16(aR1 + k0, As[nb] + 2048 + wave * 512);
#pragma unroll
      for (int w = 0; w < 3; ++w) {
        stage16(bR0[w] + k0, Bs[nb][w] + wave * 512);
        stage16(bR1[w] + k0, Bs[nb][w] + 2048 + wave * 512);
      }
    }
    // Compute current tile: 16 ds_read_b128 + 48 MFMA.
    short8 a[4];
#pragma unroll
    for (int i = 0; i < 4; ++i)
      a[i] = *(const short8*)(As[cur] + (wm + i * 16 + r) * 32 + quad * 8);
#pragma unroll
    for (int w = 0; w < 3; ++w) {
      short8 bb[4];
#pragma unroll
      for (int j = 0; j < 4; ++j)
        bb[j] = *(const short8*)(Bs[cur][w] + (wn + j * 16 + r) * 32 + quad * 8);
#pragma unroll
      for (int i = 0; i < 4; ++i)
#pragma unroll
        for (int j = 0; j < 4; ++j)
          acc[w][i][j] = __builtin_amdgcn_mfma_f32_16x16x32_bf16(a[i], bb[j], acc[w][i][j], 0, 0, 0);
    }
    STEP_FENCE();   // next tile landed (issued ~450 cyc ago) + my reads done
  }

  // Q, K: fp8 e4m3 row-major stores
  {
    unsigned char* Op[2] = {Qb, Kb};
    const float* Bp[2] = {bq, bk};
#pragma unroll
    for (int w = 0; w < 2; ++w) {
      unsigned char* out = Op[w];
#pragma unroll
      for (int j = 0; j < 4; ++j) {
        const int n = n0 + wn + j * 16 + r;
        const float bb = Bp[w][n];
#pragma unroll
        for (int i = 0; i < 4; ++i) {
          const int mbase = m0 + wm + i * 16 + quad * 4;
#pragma unroll
          for (int e = 0; e < 4; ++e)
            out[(size_t)(mbase + e) * DMODEL + n] = fp8_bits(acc[w][i][j][e] + bb);
        }
      }
    }
  }
  // V: transposed bf16 store Vt[z][d=n][pos], 8B packed per (i,j).
  {
    const int z    = m0 >> 11;           // SEQ = 2048
    const int posb = (m0 & (SEQ - 1)) + wm;
    __hip_bfloat16* vt = Vt + (size_t)z * DMODEL * SEQ;
#pragma unroll
    for (int j = 0; j < 4; ++j) {
      const int n = n0 + wn + j * 16 + r;
      const float bb = bv[n];
#pragma unroll
      for (int i = 0; i < 4; ++i) {
        const int pos = posb + i * 16 + quad * 4;
        unsigned long long pk =
            (unsigned long long)bf16_bits(acc[2][i][j][0] + bb)
          | ((unsigned long long)bf16_bits(acc[2][i][j][1] + bb) << 16)
          | ((unsigned long long)bf16_bits(acc[2][i][j][2] + bb) << 32)
          | ((unsigned long long)bf16_bits(acc[2][i][j][3] + bb) << 48);
        *(unsigned long long*)(vt + (size_t)n * SEQ + pos) = pk;
      }
    }
  }
}

// ---------------------------------------------------------------------------
// 4-wave fp8 GEMM core (R14, single-buffer 2-barrier): C[128x128] += A * B^T,
// A/B e4m3 row-major [.,K], BK=64. 16 KB LDS. Each 16B register pair = 2 fp8
// A/B-frags (kk=0,1) -> 32 MFMA/wave/barrier. k within a 16B group is
// permuted vs native MFMA order — consistent for A and B, so exact.
__device__ __forceinline__ void gemm_core_4w_fp8(
    const unsigned char* __restrict__ A,
    const unsigned char* __restrict__ B,
    int K, int m0, int n0, int kchunks,
    unsigned char* As /*128x64B*/, unsigned char* Bs /*128x64B*/,
    floatx4 acc[4][4])
{
  const int tid  = threadIdx.x;
  const int lane = tid & 63;
  const int wave = tid >> 6;          // 0..3
  const int quad = lane >> 4;
  const int r    = lane & 15;
  const int wm   = (wave >> 1) * 64;
  const int wn   = (wave & 1) * 64;
  const int lrow = lane >> 2;         // 0..15
  const int lcol = (lane & 3) * 16;   // byte col 0,16,32,48

  const unsigned char* aB = A + (size_t)(m0 + wave * 32 + lrow) * K + lcol;
  const unsigned char* bB = B + (size_t)(n0 + wave * 32 + lrow) * K + lcol;
  unsigned char* lA = As + wave * 2048;   // 2 chunks of 1024 B
  unsigned char* lB = Bs + wave * 2048;

  for (int kt = 0; kt < kchunks; ++kt) {
    const int k0 = kt * 64;
#pragma unroll
    for (int s = 0; s < 2; ++s) {
      stage16(aB + (size_t)(16 * s) * K + k0, lA + s * 1024);
      stage16(bB + (size_t)(16 * s) * K + k0, lB + s * 1024);
    }
    __syncthreads();
    longx2 a[4], b[4];
#pragma unroll
    for (int i = 0; i < 4; ++i) {
      a[i] = __builtin_bit_cast(longx2, *(const int4*)(As + (wm + i * 16 + r) * 64 + quad * 16));
      b[i] = __builtin_bit_cast(longx2, *(const int4*)(Bs + (wn + i * 16 + r) * 64 + quad * 16));
    }
#pragma unroll
    for (int kk = 0; kk < 2; ++kk)
#pragma unroll
      for (int i = 0; i < 4; ++i)
#pragma unroll
        for (int j = 0; j < 4; ++j)
          acc[i][j] = __builtin_amdgcn_mfma_f32_16x16x32_fp8_fp8(
              a[i][kk], b[j][kk], acc[i][j], 0, 0, 0);
    __syncthreads();
  }
}

// ---------------------------------------------------------------------------
// 4-wave bf16 GEMM core (R14, single-buffer 2-barrier): C[128x128] += A * B^T,
// BK=32, 16 KB LDS. If SUMS: acc_s[i] += A-frag x ones (row sums of A).
template <bool SUMS>
__device__ __forceinline__ void gemm_core_4w(
    const __hip_bfloat16* __restrict__ A,
    const __hip_bfloat16* __restrict__ B,
    int K, int m0, int n0, int kchunks,
    __hip_bfloat16* As /*128x32*/, __hip_bfloat16* Bs /*128x32*/,
    floatx4 acc[4][4], floatx4 acc_s[4])
{
  const int tid  = threadIdx.x;
  const int lane = tid & 63;
  const int wave = tid >> 6;          // 0..3
  const int quad = lane >> 4;
  const int r    = lane & 15;
  const int wm   = (wave >> 1) * 64;
  const int wn   = (wave & 1) * 64;
  const int lrow = lane >> 2;         // 0..15
  const int lcol = (lane & 3) * 8;    // 0,8,16,24

  short8 ones;
#pragma unroll
  for (int t = 0; t < 8; ++t) ones[t] = (short)0x3F80;  // bf16 1.0

  const __hip_bfloat16* aB = A + (size_t)(m0 + wave * 32 + lrow) * K + lcol;
  const __hip_bfloat16* bB = B + (size_t)(n0 + wave * 32 + lrow) * K + lcol;
  __hip_bfloat16* lA = As + wave * 1024;   // 2 chunks of 512 elems
  __hip_bfloat16* lB = Bs + wave * 1024;

  for (int kt = 0; kt < kchunks; ++kt) {
    const int k0 = kt * 32;
#pragma unroll
    for (int s = 0; s < 2; ++s) {
      stage16(aB + (size_t)(16 * s) * K + k0, lA + s * 512);
      stage16(bB + (size_t)(16 * s) * K + k0, lB + s * 512);
    }
    __syncthreads();
    short8 a[4], b[4];
#pragma unroll
    for (int i = 0; i < 4; ++i) {
      a[i] = *(const short8*)(As + (wm + i * 16 + r) * 32 + quad * 8);
      b[i] = *(const short8*)(Bs + (wn + i * 16 + r) * 32 + quad * 8);
    }
    if (SUMS) {
#pragma unroll
      for (int i = 0; i < 4; ++i)
        acc_s[i] = __builtin_amdgcn_mfma_f32_16x16x32_bf16(a[i], ones, acc_s[i], 0, 0, 0);
    }
#pragma unroll
    for (int i = 0; i < 4; ++i)
#pragma unroll
      for (int j = 0; j < 4; ++j)
        acc[i][j] = __builtin_amdgcn_mfma_f32_16x16x32_bf16(a[i], b[j], acc[i][j], 0, 0, 0);
    __syncthreads();
  }
}

// ---------------------------------------------------------------------------
// Scores: P'[z][q][k] = exp((Q_z K_z^T)[q][k]/32) for k<=q (0 in the masked
// part of diagonal tiles), stored bf16. Q,K fp8 e4m3; BK=64 4-wave core.
// 128x128 tiles; 136 lower-tri tiles per batch, compact linear index.
// XCD-contiguous ordering. grid = (544), 256 threads, 16 KB LDS.
__global__ __launch_bounds__(256, 2) void gemm_scores(
    const unsigned char* __restrict__ Qb, const unsigned char* __restrict__ Kb,
    __hip_bfloat16* __restrict__ Sb)
{
  const int b    = blockIdx.x;                 // 0..543
  const int orig = (b & 7) * 68 + (b >> 3);    // 544 = 8*68, bijective
  const int z    = orig / 136;
  const int L    = orig - z * 136;
  int mt = (int)((sqrtf(8.0f * (float)L + 1.0f) - 1.0f) * 0.5f);
  while ((mt + 1) * (mt + 2) / 2 <= L) ++mt;
  while (mt * (mt + 1) / 2 > L) --mt;
  const int nt = L - mt * (mt + 1) / 2;
  const int m0 = mt * 128, n0 = nt * 128;

  __shared__ __align__(16) unsigned char As[128 * 64];
  __shared__ __align__(16) unsigned char Bs[128 * 64];
  const unsigned char* A = Qb + (size_t)z * SEQ * DMODEL;
  const unsigned char* B = Kb + (size_t)z * SEQ * DMODEL;
  __hip_bfloat16* outp = Sb + (size_t)z * SEQ * SEQ;
  floatx4 acc[4][4] = {};
  gemm_core_4w_fp8(A, B, DMODEL, m0, n0, DMODEL / 64, As, Bs, acc);

  const int lane = threadIdx.x & 63, wave = threadIdx.x >> 6;
  const int quad = lane >> 4, r = lane & 15;
  const int wm = (wave >> 1) * 64, wn = (wave & 1) * 64;
  const float scale = 0.03125f;  // 1/sqrt(1024)
#pragma unroll
  for (int i = 0; i < 4; ++i) {
    const int mbase = m0 + wm + i * 16 + quad * 4;
#pragma unroll
    for (int e = 0; e < 4; ++e) {
      const int row = mbase + e;
#pragma unroll
      for (int j = 0; j < 4; ++j) {
        const int n = n0 + wn + j * 16 + r;
        const float pv = (n <= row) ? __expf(acc[i][j][e] * scale) : 0.f;
        outp[(size_t)row * SEQ + n] = __float2bfloat16(pv);
      }
    }
  }
}

// ---------------------------------------------------------------------------
// PV: Out[z][q][d] = (P'_z @ Vt_z^T)[q][d] / rowsum(P'), fp32 out.
// Row sums via the ones-MFMA. 128x128 tiles, bf16 BK=32 4-wave core; K
// truncated at the diagonal.
// R25 decode: per-XCD balanced pairing. rank = slot>>3 (issue rank, 8 groups
// of 8 n-blocks); gi = rank<4 ? rank : 11-rank gives group order
// {hi,hi-1,hi-2,hi-3, lo,lo+1,lo+2,lo+3} so under linear CU fill (CU hosts
// slots c and c+32) every CU's two blocks sum to the SAME kchunk total
// (72 units on odd-mt XCDs, 64 on even): makespan = mean, not max.
// grid = (512), 256 threads, 16 KB LDS.
__global__ __launch_bounds__(256, 2) void gemm_pv(
    const __hip_bfloat16* __restrict__ Sb, const __hip_bfloat16* __restrict__ Vt,
    float* __restrict__ Out)
{
  const int b    = blockIdx.x;     // 0..511
  const int xcd  = b & 7;
  const int slot = b >> 3;         // 0..63 within XCD
  const int rank = slot >> 3;      // issue rank 0..7
  const int gi   = (rank < 4) ? rank : 11 - rank;  // balanced pairing perm
  const int q    = gi * 8 + xcd;   // global group id
  const int n0   = (slot & 7) * 128;
  const int z    = q & 3;
  const int mt   = 15 - (q >> 2);  // gi 0 -> longest K
  const int m0   = mt * 128;

  __shared__ __align__(16) __hip_bfloat16 As[128 * 32];
  __shared__ __align__(16) __hip_bfloat16 Bs[128 * 32];
  const __hip_bfloat16* A = Sb + (size_t)z * SEQ * SEQ;
  const __hip_bfloat16* B = Vt + (size_t)z * DMODEL * SEQ;
  float* outp = Out + (size_t)z * SEQ * DMODEL;

  floatx4 acc[4][4] = {};
  floatx4 acc_s[4] = {};
  const int kchunks = 4 * mt + 4;   // (m0+128)/32: causal truncation
  gemm_core_4w<true>(A, B, SEQ, m0, n0, kchunks, As, Bs, acc, acc_s);

  const int lane = threadIdx.x & 63, wave = threadIdx.x >> 6;
  const int quad = lane >> 4, r = lane & 15;
  const int wm = (wave >> 1) * 64, wn = (wave & 1) * 64;
#pragma unroll
  for (int i = 0; i < 4; ++i) {
    const int mbase = m0 + wm + i * 16 + quad * 4;
    float inv[4];
#pragma unroll
    for (int e = 0; e < 4; ++e) inv[e] = 1.f / acc_s[i][e];
#pragma unroll
    for (int j = 0; j < 4; ++j) {
      const int n = n0 + wn + j * 16 + r;
#pragma unroll
      for (int e = 0; e < 4; ++e)
        outp[(size_t)(mbase + e) * DMODEL + n] = acc[i][j][e] * inv[e];
    }
  }
}

// ---------------------------------------------------------------------------
extern "C" void kernel_launch(void* const* d_in, const int* in_sizes, int n_in,
                              void* d_out, int out_size, void* d_ws, size_t ws_size,
                              hipStream_t stream)
{
  const float* X  = (const float*)d_in[0];
  const float* Wq = (const float*)d_in[1];
  const float* bq = (const float*)d_in[2];
  const float* Wk = (const float*)d_in[3];
  const float* bk = (const float*)d_in[4];
  const float* Wv = (const float*)d_in[5];
  const float* bv = (const float*)d_in[6];
  float* Out = (float*)d_out;

  // Workspace layout (~87 MB total)
  char* ws = (char*)d_ws;
  size_t off = 0;
  auto alloc = [&](size_t bytes) -> void* {
    void* p = ws + off;
    off += (bytes + 255) & ~(size_t)255;
    return p;
  };
  __hip_bfloat16* Xb  = (__hip_bfloat16*)alloc((size_t)MTOT * DMODEL * 2);    // 16 MB
  __hip_bfloat16* Wqb = (__hip_bfloat16*)alloc((size_t)DMODEL * DMODEL * 2);  // 2 MB
  __hip_bfloat16* Wkb = (__hip_bfloat16*)alloc((size_t)DMODEL * DMODEL * 2);
  __hip_bfloat16* Wvb = (__hip_bfloat16*)alloc((size_t)DMODEL * DMODEL * 2);
  unsigned char*  Qb  = (unsigned char*)alloc((size_t)MTOT * DMODEL);         // 8 MB (fp8)
  unsigned char*  Kb  = (unsigned char*)alloc((size_t)MTOT * DMODEL);         // 8 MB (fp8)
  __hip_bfloat16* Vt  = (__hip_bfloat16*)alloc((size_t)MTOT * DMODEL * 2);    // 16 MB
  __hip_bfloat16* Sb  = (__hip_bfloat16*)alloc((size_t)NBATCH * SEQ * SEQ * 2); // 32 MB
  (void)ws_size; (void)in_sizes; (void)n_in; (void)out_size;

  // 1) converts (one kernel)
  convert_all<<<11264, 256, 0, stream>>>(X, Wq, Wk, Wv, Xb, Wqb, Wkb, Wvb);
  // 2) fused QKV projection, prefetch-1 dbuf (measured 60us)
  gemm_qkv_db<<<512, 256, 0, stream>>>(
      Xb, Wqb, Wkb, Wvb, bq, bk, bv, Qb, Kb, Vt);
  // 3) scores: R14 single-buffer fp8 BK=64 core, tri-compact + XCD swizzle
  gemm_scores<<<dim3(544), 256, 0, stream>>>(Qb, Kb, Sb);
  // 4) PV: single-buffer bf16 core, balanced-pair XCD deal, sums + normalize
  gemm_pv<<<dim3(512), 256, 0, stream>>>(Sb, Vt, Out);
}

// Round 15
// 208.035 us; speedup vs baseline: 1.0613x; 1.0285x over previous
//
#include <hip/hip_runtime.h>
#include <hip/hip_bf16.h>
#include <hip/hip_fp8.h>

// Self-attention: q=X@Wq.T+bq, k=..., v=...; S = causal_softmax(q k^T / 32); O = S v
// B=4, S=2048, D_IN=D_OUT=1024. fp32 in/out; internal bf16/fp8 MFMA + fp32 acc.
//
// R28 = R27 resubmitted verbatim (R27 bench failed on GPU acquisition).
// R27 change (post-mortem of R25-neutral): scores/pv are fence-bound, not
// staging/balance-bound (R20/21/24/25 all null on those axes). Their per-fence
// MFMA counts (32 / 20) are half of qkv's 48, which runs 2x their efficiency
// with the SAME core. => double K per fence by staging TWO byte-identical
// copies of the proven 64B-row half-tile (lo-k, hi-k) per step:
//  - pv:    BK=64  (2 x [128][32]bf16 per matrix), 40 MFMA/fence, steps 34->17
//  - scores:BK=128 (2 x [128][64B]fp8 per matrix), 64 MFMA/fence, steps 16->8
// Same staging map, same ds_read addressing, same bank behavior as measured
// cores; LDS 32 KB each, 2 blk/CU preserved. qkv / convert / epilogues
// byte-identical to R25 (214.0us measured); pv keeps the neutral balanced deal.
//
// MFMA fragment layouts (HW-verified per guide §3):
//  A: lane holds A[m=lane&15][k=(lane>>4)*8+j], j=0..7
//  B: lane holds B[k=(lane>>4)*8+j][n=lane&15]
//  C/D: lane holds D[row=(lane>>4)*4+e][col=lane&15], e=0..3

typedef __attribute__((ext_vector_type(8))) short short8;   // 8 bf16 = 4 VGPRs
typedef __attribute__((ext_vector_type(4))) float floatx4;  // MFMA acc
typedef __attribute__((ext_vector_type(2))) long longx2;    // 16B = 2 fp8 frags

#define SEQ   2048
#define DMODEL 1024
#define NBATCH 4
#define MTOT  (SEQ * NBATCH)

// End-of-step fence for the qkv dbuf core.
#define STEP_FENCE() do {                                              \
    asm volatile("s_waitcnt vmcnt(0) lgkmcnt(0)" ::: "memory");        \
    __builtin_amdgcn_sched_barrier(0);                                 \
    __builtin_amdgcn_s_barrier(); } while (0)

// Direct global->LDS async copy, 16B per lane. LDS dst is wave-uniform base +
// lane*16 (per-lane scatter NOT supported).
__device__ __forceinline__ void stage16(const void* g, void* l)
{
  __builtin_amdgcn_global_load_lds(
      (const __attribute__((address_space(1))) void*)g,
      (__attribute__((address_space(3))) void*)l, 16, 0, 0);
}

__device__ __forceinline__ unsigned short bf16_bits(float f)
{
  __hip_bfloat16 h = __float2bfloat16(f);
  return *(unsigned short*)&h;
}

__device__ __forceinline__ unsigned char fp8_bits(float f)
{
  __hip_fp8_e4m3 h(f);            // OCP e4m3 (gfx950), not fnuz
  return h.__x;
}

// ---------------------------------------------------------------------------
// One-kernel fp32 -> bf16 convert for all four inputs. Each block: 1024 elems.
__global__ __launch_bounds__(256) void convert_all(
    const float* __restrict__ X,  const float* __restrict__ Wq,
    const float* __restrict__ Wk, const float* __restrict__ Wv,
    __hip_bfloat16* __restrict__ Xb,  __hip_bfloat16* __restrict__ Wqb,
    __hip_bfloat16* __restrict__ Wkb, __hip_bfloat16* __restrict__ Wvb)
{
  const int b = blockIdx.x;
  const float* src; __hip_bfloat16* dst; int rel;
  if (b < 8192)       { src = X;  dst = Xb;  rel = b; }
  else if (b < 9216)  { src = Wq; dst = Wqb; rel = b - 8192; }
  else if (b < 10240) { src = Wk; dst = Wkb; rel = b - 9216; }
  else                { src = Wv; dst = Wvb; rel = b - 10240; }
  const int i = rel * 1024 + threadIdx.x * 4;
  float4 f = *(const float4*)(src + i);
  uint2 o;
  o.x = (unsigned)bf16_bits(f.x) | ((unsigned)bf16_bits(f.y) << 16);
  o.y = (unsigned)bf16_bits(f.z) | ((unsigned)bf16_bits(f.w) << 16);
  *(uint2*)(dst + i) = o;
}

// ---------------------------------------------------------------------------
// Fused QKV projection, prefetch-1 double-buffered (measured 60.6us, R20).
// 4 waves, tile 128(m) x 128(n) x {Q,K,V}, BK=32, 48 MFMA/wave/step between
// single barriers. LDS 2 x (8+24) = 64 KB. Q,K stored fp8 e4m3 row-major;
// V stored bf16 transposed to Vt. grid = 512 flat (XCD-chunked, mt-grouped),
// 256 threads.
__global__ __launch_bounds__(256, 2) void gemm_qkv_db(
    const __hip_bfloat16* __restrict__ Xb,
    const __hip_bfloat16* __restrict__ Wqb,
    const __hip_bfloat16* __restrict__ Wkb,
    const __hip_bfloat16* __restrict__ Wvb,
    const float* __restrict__ bq, const float* __restrict__ bk, const float* __restrict__ bv,
    unsigned char* __restrict__ Qb, unsigned char* __restrict__ Kb,
    __hip_bfloat16* __restrict__ Vt)
{
  __shared__ __hip_bfloat16 As[2][128 * 32];      // 2 x 8 KB
  __shared__ __hip_bfloat16 Bs[2][3][128 * 32];   // 2 x 24 KB

  // XCD-chunked bijective swizzle (512 % 8 == 0), mt-grouped.
  const int b    = blockIdx.x;                 // 0..511
  const int orig = (b & 7) * 64 + (b >> 3);
  const int mt = orig >> 3, ng = orig & 7;
  const int m0 = mt * 128, n0 = ng * 128;

  const int tid  = threadIdx.x;
  const int lane = tid & 63;
  const int wave = tid >> 6;                   // 0..3
  const int quad = lane >> 4;
  const int r    = lane & 15;
  const int wm   = (wave >> 1) * 64;
  const int wn   = (wave & 1) * 64;
  const int srow = wave * 16 + (lane >> 2);    // 0..63
  const int scol = (lane & 3) * 8;             // 0,8,16,24

  const __hip_bfloat16* aR0 = Xb + (size_t)(m0 + srow) * DMODEL + scol;
  const __hip_bfloat16* aR1 = aR0 + (size_t)64 * DMODEL;
  const __hip_bfloat16* bR0[3], * bR1[3];
  {
    const __hip_bfloat16* Wp[3] = {Wqb, Wkb, Wvb};
#pragma unroll
    for (int w = 0; w < 3; ++w) {
      bR0[w] = Wp[w] + (size_t)(n0 + srow) * DMODEL + scol;
      bR1[w] = bR0[w] + (size_t)64 * DMODEL;
    }
  }

  floatx4 acc[3][4][4] = {};

  // Prologue: stage K-tile 0 into buffer 0, wait, publish.
  {
    stage16(aR0, As[0] + wave * 512);
    stage16(aR1, As[0] + 2048 + wave * 512);
#pragma unroll
    for (int w = 0; w < 3; ++w) {
      stage16(bR0[w], Bs[0][w] + wave * 512);
      stage16(bR1[w], Bs[0][w] + 2048 + wave * 512);
    }
    asm volatile("s_waitcnt vmcnt(0)" ::: "memory");
    __builtin_amdgcn_sched_barrier(0);
    __builtin_amdgcn_s_barrier();
  }

  for (int kt = 0; kt < 32; ++kt) {
    const int cur = kt & 1;
    // Issue next tile's staging FIRST (hides under this tile's compute).
    if (kt < 31) {
      const int k0 = (kt + 1) * 32, nb = cur ^ 1;
      stage16(aR0 + k0, As[nb] + wave * 512);
      stage16(aR1 + k0, As[nb] + 2048 + wave * 512);
#pragma unroll
      for (int w = 0; w < 3; ++w) {
        stage16(bR0[w] + k0, Bs[nb][w] + wave * 512);
        stage16(bR1[w] + k0, Bs[nb][w] + 2048 + wave * 512);
      }
    }
    // Compute current tile: 16 ds_read_b128 + 48 MFMA.
    short8 a[4];
#pragma unroll
    for (int i = 0; i < 4; ++i)
      a[i] = *(const short8*)(As[cur] + (wm + i * 16 + r) * 32 + quad * 8);
#pragma unroll
    for (int w = 0; w < 3; ++w) {
      short8 bb[4];
#pragma unroll
      for (int j = 0; j < 4; ++j)
        bb[j] = *(const short8*)(Bs[cur][w] + (wn + j * 16 + r) * 32 + quad * 8);
#pragma unroll
      for (int i = 0; i < 4; ++i)
#pragma unroll
        for (int j = 0; j < 4; ++j)
          acc[w][i][j] = __builtin_amdgcn_mfma_f32_16x16x32_bf16(a[i], bb[j], acc[w][i][j], 0, 0, 0);
    }
    STEP_FENCE();   // next tile landed (issued ~450 cyc ago) + my reads done
  }

  // Q, K: fp8 e4m3 row-major stores
  {
    unsigned char* Op[2] = {Qb, Kb};
    const float* Bp[2] = {bq, bk};
#pragma unroll
    for (int w = 0; w < 2; ++w) {
      unsigned char* out = Op[w];
#pragma unroll
      for (int j = 0; j < 4; ++j) {
        const int n = n0 + wn + j * 16 + r;
        const float bb = Bp[w][n];
#pragma unroll
        for (int i = 0; i < 4; ++i) {
          const int mbase = m0 + wm + i * 16 + quad * 4;
#pragma unroll
          for (int e = 0; e < 4; ++e)
            out[(size_t)(mbase + e) * DMODEL + n] = fp8_bits(acc[w][i][j][e] + bb);
        }
      }
    }
  }
  // V: transposed bf16 store Vt[z][d=n][pos], 8B packed per (i,j).
  {
    const int z    = m0 >> 11;           // SEQ = 2048
    const int posb = (m0 & (SEQ - 1)) + wm;
    __hip_bfloat16* vt = Vt + (size_t)z * DMODEL * SEQ;
#pragma unroll
    for (int j = 0; j < 4; ++j) {
      const int n = n0 + wn + j * 16 + r;
      const float bb = bv[n];
#pragma unroll
      for (int i = 0; i < 4; ++i) {
        const int pos = posb + i * 16 + quad * 4;
        unsigned long long pk =
            (unsigned long long)bf16_bits(acc[2][i][j][0] + bb)
          | ((unsigned long long)bf16_bits(acc[2][i][j][1] + bb) << 16)
          | ((unsigned long long)bf16_bits(acc[2][i][j][2] + bb) << 32)
          | ((unsigned long long)bf16_bits(acc[2][i][j][3] + bb) << 48);
        *(unsigned long long*)(vt + (size_t)n * SEQ + pos) = pk;
      }
    }
  }
}

// ---------------------------------------------------------------------------
// 4-wave fp8 GEMM core, BK=128 as two proven 64B-row half-tiles (lo/hi k):
// C[128x128] += A * B^T, A/B e4m3 row-major [.,K]. Per step: 8 stage16,
// 16 ds_read_b128, 64 MFMA, one barrier pair. LDS 2 x (8+8) = 32 KB.
// Each half is byte-identical in geometry to the measured BK=64 core.
__device__ __forceinline__ void gemm_core_4w_fp8_k128(
    const unsigned char* __restrict__ A,
    const unsigned char* __restrict__ B,
    int K, int m0, int n0, int kchunks128,
    unsigned char (*As)[128 * 64], unsigned char (*Bs)[128 * 64],
    floatx4 acc[4][4])
{
  const int tid  = threadIdx.x;
  const int lane = tid & 63;
  const int wave = tid >> 6;          // 0..3
  const int quad = lane >> 4;
  const int r    = lane & 15;
  const int wm   = (wave >> 1) * 64;
  const int wn   = (wave & 1) * 64;
  const int lrow = lane >> 2;         // 0..15
  const int lcol = (lane & 3) * 16;   // byte col 0,16,32,48

  const unsigned char* aB = A + (size_t)(m0 + wave * 32 + lrow) * K + lcol;
  const unsigned char* bB = B + (size_t)(n0 + wave * 32 + lrow) * K + lcol;

  for (int kt = 0; kt < kchunks128; ++kt) {
    const int k0 = kt * 128;
#pragma unroll
    for (int h = 0; h < 2; ++h)       // half: cols k0+64h .. k0+64h+63
#pragma unroll
      for (int s = 0; s < 2; ++s) {
        stage16(aB + (size_t)(16 * s) * K + k0 + 64 * h, As[h] + wave * 2048 + s * 1024);
        stage16(bB + (size_t)(16 * s) * K + k0 + 64 * h, Bs[h] + wave * 2048 + s * 1024);
      }
    __syncthreads();
    longx2 a[2][4], bb[2][4];
#pragma unroll
    for (int h = 0; h < 2; ++h)
#pragma unroll
      for (int i = 0; i < 4; ++i) {
        a[h][i]  = __builtin_bit_cast(longx2, *(const int4*)(As[h] + (wm + i * 16 + r) * 64 + quad * 16));
        bb[h][i] = __builtin_bit_cast(longx2, *(const int4*)(Bs[h] + (wn + i * 16 + r) * 64 + quad * 16));
      }
#pragma unroll
    for (int h = 0; h < 2; ++h)
#pragma unroll
      for (int kk = 0; kk < 2; ++kk)
#pragma unroll
        for (int i = 0; i < 4; ++i)
#pragma unroll
          for (int j = 0; j < 4; ++j)
            acc[i][j] = __builtin_amdgcn_mfma_f32_16x16x32_fp8_fp8(
                a[h][i][kk], bb[h][j][kk], acc[i][j], 0, 0, 0);
    __syncthreads();
  }
}

// ---------------------------------------------------------------------------
// 4-wave bf16 GEMM core, BK=64 as two proven 64B-row half-tiles (lo/hi k):
// C[128x128] += A * B^T. Per step: 8 stage16, 16 ds_read_b128, 32 (+8 sums)
// MFMA, one barrier pair. LDS 2 x (8+8) = 32 KB.
// If SUMS: acc_s[i] += A-frag x ones (row sums of A in C-layout, fp32).
template <bool SUMS>
__device__ __forceinline__ void gemm_core_4w_k64(
    const __hip_bfloat16* __restrict__ A,
    const __hip_bfloat16* __restrict__ B,
    int K, int m0, int n0, int kchunks64,
    __hip_bfloat16 (*As)[128 * 32], __hip_bfloat16 (*Bs)[128 * 32],
    floatx4 acc[4][4], floatx4 acc_s[4])
{
  const int tid  = threadIdx.x;
  const int lane = tid & 63;
  const int wave = tid >> 6;          // 0..3
  const int quad = lane >> 4;
  const int r    = lane & 15;
  const int wm   = (wave >> 1) * 64;
  const int wn   = (wave & 1) * 64;
  const int lrow = lane >> 2;         // 0..15
  const int lcol = (lane & 3) * 8;    // 0,8,16,24

  short8 ones;
#pragma unroll
  for (int t = 0; t < 8; ++t) ones[t] = (short)0x3F80;  // bf16 1.0

  const __hip_bfloat16* aB = A + (size_t)(m0 + wave * 32 + lrow) * K + lcol;
  const __hip_bfloat16* bB = B + (size_t)(n0 + wave * 32 + lrow) * K + lcol;

  for (int kt = 0; kt < kchunks64; ++kt) {
    const int k0 = kt * 64;
#pragma unroll
    for (int h = 0; h < 2; ++h)       // half: cols k0+32h .. k0+32h+31
#pragma unroll
      for (int s = 0; s < 2; ++s) {
        stage16(aB + (size_t)(16 * s) * K + k0 + 32 * h, As[h] + wave * 1024 + s * 512);
        stage16(bB + (size_t)(16 * s) * K + k0 + 32 * h, Bs[h] + wave * 1024 + s * 512);
      }
    __syncthreads();
    short8 a[2][4], bb[2][4];
#pragma unroll
    for (int h = 0; h < 2; ++h)
#pragma unroll
      for (int i = 0; i < 4; ++i) {
        a[h][i]  = *(const short8*)(As[h] + (wm + i * 16 + r) * 32 + quad * 8);
        bb[h][i] = *(const short8*)(Bs[h] + (wn + i * 16 + r) * 32 + quad * 8);
      }
    if (SUMS) {
#pragma unroll
      for (int h = 0; h < 2; ++h)
#pragma unroll
        for (int i = 0; i < 4; ++i)
          acc_s[i] = __builtin_amdgcn_mfma_f32_16x16x32_bf16(a[h][i], ones, acc_s[i], 0, 0, 0);
    }
#pragma unroll
    for (int h = 0; h < 2; ++h)
#pragma unroll
      for (int i = 0; i < 4; ++i)
#pragma unroll
        for (int j = 0; j < 4; ++j)
          acc[i][j] = __builtin_amdgcn_mfma_f32_16x16x32_bf16(a[h][i], bb[h][j], acc[i][j], 0, 0, 0);
    __syncthreads();
  }
}

// ---------------------------------------------------------------------------
// Scores: P'[z][q][k] = exp((Q_z K_z^T)[q][k]/32) for k<=q (0 in the masked
// part of diagonal tiles), stored bf16. Q,K fp8 e4m3; BK=128 two-half core.
// 128x128 tiles; 136 lower-tri tiles per batch, compact linear index.
// XCD-contiguous ordering. grid = (544), 256 threads, 32 KB LDS.
__global__ __launch_bounds__(256, 2) void gemm_scores(
    const unsigned char* __restrict__ Qb, const unsigned char* __restrict__ Kb,
    __hip_bfloat16* __restrict__ Sb)
{
  const int b    = blockIdx.x;                 // 0..543
  const int orig = (b & 7) * 68 + (b >> 3);    // 544 = 8*68, bijective
  const int z    = orig / 136;
  const int L    = orig - z * 136;
  int mt = (int)((sqrtf(8.0f * (float)L + 1.0f) - 1.0f) * 0.5f);
  while ((mt + 1) * (mt + 2) / 2 <= L) ++mt;
  while (mt * (mt + 1) / 2 > L) --mt;
  const int nt = L - mt * (mt + 1) / 2;
  const int m0 = mt * 128, n0 = nt * 128;

  __shared__ __align__(16) unsigned char As[2][128 * 64];
  __shared__ __align__(16) unsigned char Bs[2][128 * 64];
  const unsigned char* A = Qb + (size_t)z * SEQ * DMODEL;
  const unsigned char* B = Kb + (size_t)z * SEQ * DMODEL;
  __hip_bfloat16* outp = Sb + (size_t)z * SEQ * SEQ;
  floatx4 acc[4][4] = {};
  gemm_core_4w_fp8_k128(A, B, DMODEL, m0, n0, DMODEL / 128, As, Bs, acc);

  const int lane = threadIdx.x & 63, wave = threadIdx.x >> 6;
  const int quad = lane >> 4, r = lane & 15;
  const int wm = (wave >> 1) * 64, wn = (wave & 1) * 64;
  const float scale = 0.03125f;  // 1/sqrt(1024)
#pragma unroll
  for (int i = 0; i < 4; ++i) {
    const int mbase = m0 + wm + i * 16 + quad * 4;
#pragma unroll
    for (int e = 0; e < 4; ++e) {
      const int row = mbase + e;
#pragma unroll
      for (int j = 0; j < 4; ++j) {
        const int n = n0 + wn + j * 16 + r;
        const float pv = (n <= row) ? __expf(acc[i][j][e] * scale) : 0.f;
        outp[(size_t)row * SEQ + n] = __float2bfloat16(pv);
      }
    }
  }
}

// ---------------------------------------------------------------------------
// PV: Out[z][q][d] = (P'_z @ Vt_z^T)[q][d] / rowsum(P'), fp32 out.
// Row sums via the ones-MFMA. 128x128 tiles, bf16 BK=64 two-half core; K
// truncated at the diagonal. Balanced-pair XCD deal (R25, measured-neutral).
// grid = (512), 256 threads, 32 KB LDS.
__global__ __launch_bounds__(256, 2) void gemm_pv(
    const __hip_bfloat16* __restrict__ Sb, const __hip_bfloat16* __restrict__ Vt,
    float* __restrict__ Out)
{
  const int b    = blockIdx.x;     // 0..511
  const int xcd  = b & 7;
  const int slot = b >> 3;         // 0..63 within XCD
  const int rank = slot >> 3;      // issue rank 0..7
  const int gi   = (rank < 4) ? rank : 11 - rank;  // balanced pairing perm
  const int q    = gi * 8 + xcd;   // global group id
  const int n0   = (slot & 7) * 128;
  const int z    = q & 3;
  const int mt   = 15 - (q >> 2);  // gi 0 -> longest K
  const int m0   = mt * 128;

  __shared__ __align__(16) __hip_bfloat16 As[2][128 * 32];
  __shared__ __align__(16) __hip_bfloat16 Bs[2][128 * 32];
  const __hip_bfloat16* A = Sb + (size_t)z * SEQ * SEQ;
  const __hip_bfloat16* B = Vt + (size_t)z * DMODEL * SEQ;
  float* outp = Out + (size_t)z * SEQ * DMODEL;

  floatx4 acc[4][4] = {};
  floatx4 acc_s[4] = {};
  const int kchunks64 = 2 * mt + 2;   // (m0+128)/64: causal truncation
  gemm_core_4w_k64<true>(A, B, SEQ, m0, n0, kchunks64, As, Bs, acc, acc_s);

  const int lane = threadIdx.x & 63, wave = threadIdx.x >> 6;
  const int quad = lane >> 4, r = lane & 15;
  const int wm = (wave >> 1) * 64, wn = (wave & 1) * 64;
#pragma unroll
  for (int i = 0; i < 4; ++i) {
    const int mbase = m0 + wm + i * 16 + quad * 4;
    float inv[4];
#pragma unroll
    for (int e = 0; e < 4; ++e) inv[e] = 1.f / acc_s[i][e];
#pragma unroll
    for (int j = 0; j < 4; ++j) {
      const int n = n0 + wn + j * 16 + r;
#pragma unroll
      for (int e = 0; e < 4; ++e)
        outp[(size_t)(mbase + e) * DMODEL + n] = acc[i][j][e] * inv[e];
    }
  }
}

// ---------------------------------------------------------------------------
extern "C" void kernel_launch(void* const* d_in, const int* in_sizes, int n_in,
                              void* d_out, int out_size, void* d_ws, size_t ws_size,
                              hipStream_t stream)
{
  const float* X  = (const float*)d_in[0];
  const float* Wq = (const float*)d_in[1];
  const float* bq = (const float*)d_in[2];
  const float* Wk = (const float*)d_in[3];
  const float* bk = (const float*)d_in[4];
  const float* Wv = (const float*)d_in[5];
  const float* bv = (const float*)d_in[6];
  float* Out = (float*)d_out;

  // Workspace layout (~87 MB total)
  char* ws = (char*)d_ws;
  size_t off = 0;
  auto alloc = [&](size_t bytes) -> void* {
    void* p = ws + off;
    off += (bytes + 255) & ~(size_t)255;
    return p;
  };
  __hip_bfloat16* Xb  = (__hip_bfloat16*)alloc((size_t)MTOT * DMODEL * 2);    // 16 MB
  __hip_bfloat16* Wqb = (__hip_bfloat16*)alloc((size_t)DMODEL * DMODEL * 2);  // 2 MB
  __hip_bfloat16* Wkb = (__hip_bfloat16*)alloc((size_t)DMODEL * DMODEL * 2);
  __hip_bfloat16* Wvb = (__hip_bfloat16*)alloc((size_t)DMODEL * DMODEL * 2);
  unsigned char*  Qb  = (unsigned char*)alloc((size_t)MTOT * DMODEL);         // 8 MB (fp8)
  unsigned char*  Kb  = (unsigned char*)alloc((size_t)MTOT * DMODEL);         // 8 MB (fp8)
  __hip_bfloat16* Vt  = (__hip_bfloat16*)alloc((size_t)MTOT * DMODEL * 2);    // 16 MB
  __hip_bfloat16* Sb  = (__hip_bfloat16*)alloc((size_t)NBATCH * SEQ * SEQ * 2); // 32 MB
  (void)ws_size; (void)in_sizes; (void)n_in; (void)out_size;

  // 1) converts (one kernel)
  convert_all<<<11264, 256, 0, stream>>>(X, Wq, Wk, Wv, Xb, Wqb, Wkb, Wvb);
  // 2) fused QKV projection, prefetch-1 dbuf (measured 60us)
  gemm_qkv_db<<<512, 256, 0, stream>>>(
      Xb, Wqb, Wkb, Wvb, bq, bk, bv, Qb, Kb, Vt);
  // 3) scores: fp8 BK=128 two-half core, tri-compact + XCD swizzle
  gemm_scores<<<dim3(544), 256, 0, stream>>>(Qb, Kb, Sb);
  // 4) PV: bf16 BK=64 two-half core, balanced-pair deal, sums + normalize
  gemm_pv<<<dim3(512), 256, 0, stream>>>(Sb, Vt, Out);
}